// Round 3
// baseline (395.545 us; speedup 1.0000x reference)
//
#include <hip/hip_runtime.h>

#define NT 4096          // time samples per column
#define NCOL 4096        // 512 traces * 8 channels
#define EPT 32           // elements per lane: a wave PAIR (128 lanes) sorts one column
#define BLOCK 512        // 8 waves: {pred,obs} x {col 0,1} x {wave-of-pair 0,1}
#define NBLOCKS 2048     // 4096 cols / 2 cols per block

__device__ __forceinline__ float b2f(int i) { return __builtin_bit_cast(float, i); }
__device__ __forceinline__ int   f2b(float f) { return __builtin_bit_cast(int, f); }

// Cross-lane fetch of partner lane^XM's value.
// XM 1,2,3 (quad_perm), 7 (row_half_mirror), 8 (row_ror:8), 15 (row_mirror): DPP,
// VALU pipe, zero DS traffic. XM 4,16,31: ds_swizzle. XM 32,63: ds_bpermute
// (ds_swizzle xor-mask is 5-bit, cannot cross the 32-lane halves).
template <int XM>
__device__ __forceinline__ float lx(float v) {
    const int i = f2b(v);
    int r;
    if constexpr (XM == 1)       r = __builtin_amdgcn_update_dpp(0, i, 0xB1,  0xF, 0xF, true);
    else if constexpr (XM == 2)  r = __builtin_amdgcn_update_dpp(0, i, 0x4E,  0xF, 0xF, true);
    else if constexpr (XM == 3)  r = __builtin_amdgcn_update_dpp(0, i, 0x1B,  0xF, 0xF, true);
    else if constexpr (XM == 7)  r = __builtin_amdgcn_update_dpp(0, i, 0x141, 0xF, 0xF, true);
    else if constexpr (XM == 8)  r = __builtin_amdgcn_update_dpp(0, i, 0x128, 0xF, 0xF, true);
    else if constexpr (XM == 15) r = __builtin_amdgcn_update_dpp(0, i, 0x140, 0xF, 0xF, true);
    else if constexpr (XM == 4)  r = __builtin_amdgcn_ds_swizzle(i, 0x101F);
    else if constexpr (XM == 16) r = __builtin_amdgcn_ds_swizzle(i, 0x401F);
    else if constexpr (XM == 31) r = __builtin_amdgcn_ds_swizzle(i, 0x7C1F);
    else {
        const int lane = (int)(threadIdx.x & 63);
        r = __builtin_amdgcn_ds_bpermute((lane ^ XM) << 2, i);
    }
    return b2f(r);
}

__device__ __forceinline__ void cemin(float& a, float& b) {
    const float lo = fminf(a, b);
    const float hi = fmaxf(a, b);
    a = lo; b = hi;
}
__device__ __forceinline__ float csel(float x, float y, bool keep_min) {
    return ((x < y) == keep_min) ? x : y;
}

// plain cross-lane stage, lane-xor M, same element index
template <int M>
__device__ __forceinline__ void plain_stage(float (&x)[EPT], int L) {
    const bool km = (L & M) == 0;
    #pragma unroll
    for (int e = 0; e < EPT; ++e) {
        const float y = lx<M>(x[e]);
        x[e] = csel(x[e], y, km);
    }
}

template <int M>
__device__ __forceinline__ void plains_down(float (&x)[EPT], int L) {
    plain_stage<M>(x, L);
    if constexpr (M > 1) plains_down<M / 2>(x, L);
}

// intra-thread plain stages j = 16..1, all ascending (normalized network)
__device__ __forceinline__ void tail16(float (&x)[EPT]) {
    #pragma unroll
    for (int j = 16; j >= 1; j >>= 1) {
        #pragma unroll
        for (int e = 0; e < EPT; ++e)
            if ((e & j) == 0) cemin(x[e], x[e | j]);
    }
}

// Normalized bitonic merge of size k = 32*K (K = 2..64), fully in-wave:
// reversal: partner lane L^(K-1), element mirror e<->31-e, keep-min if (L&K/2)==0;
// then plain lane-xor stages m=K/4..1; then intra-thread tail j=16..1.
template <int K>
__device__ __forceinline__ void cross_merge(float (&x)[EPT], int L) {
    const bool km = (L & (K >> 1)) == 0;
    #pragma unroll
    for (int e = 0; e < EPT / 2; ++e) {
        const float ylo = lx<K - 1>(x[EPT - 1 - e]);   // partner's mirrored element
        const float yhi = lx<K - 1>(x[e]);
        x[e]           = csel(x[e], ylo, km);
        x[EPT - 1 - e] = csel(x[EPT - 1 - e], yhi, km);
    }
    if constexpr (K >= 4) plains_down<K / 4>(x, L);
    tail16(x);
}

// LDS (one union, phases are sequential):
//   staging transpose: 2 halves x 2 cols x 2048 words            = 8192 words
//   k=4096 exchange:   (half*2+col) regions x 2048 words         = 8192 words
//   epilogue strips:   2 regions x 2 cols x 2048 words           = 8192 words
#define LS_WORDS 8448

__global__ __launch_bounds__(512, 6) void wass_kernel(const float* __restrict__ pred,
                                                      const float* __restrict__ obs,
                                                      float* __restrict__ out) {
    __shared__ __align__(16) float ls[LS_WORDS];

    const int bid  = blockIdx.x;
    const int cb   = (bid & 7) * 256 + (bid >> 3);   // XCD-band col-block swizzle
    const int col0 = cb * 2;

    const int t    = threadIdx.x;
    const int half = t >> 8;           // 0 = pred, 1 = obs
    const int ht   = t & 255;          // thread within half
    const int wh   = ht >> 6;          // wave within half: 0..3
    const int w2   = wh >> 1;          // column (0..1) this wave-pair sorts
    const int wp   = wh & 1;           // which wave of the pair
    const int L    = t & 63;           // lane
    const int P    = wp * 64 + L;      // 0..127: position of this lane in the pair

    const float* __restrict__ src = half ? obs : pred;

    // ---- staged load + transpose: 2 chunks of 2048 rows, loads all issued
    // up front so HBM latency hides under chunk-0's LDS work ----
    // local row lr = (r>>5)*16 + (r&15); LDS word = (lr&~31)|((lr&31)^((lr>>5)&15)):
    // writer and reader both land at <=2-way bank aliasing (free).
    float x[EPT];
    {
        float* stg = ls + half * 4096;
        const int b_w = ht >> 1;           // row-block (0..127) this thread loads
        const int lo  = ht & 1;
        float2 v[2][8];
        #pragma unroll
        for (int q = 0; q < 2; ++q) {
            #pragma unroll
            for (int k = 0; k < 8; ++k) {
                const int r = b_w * 32 + q * 16 + lo * 8 + k;
                v[q][k] = *(const float2*)&src[(size_t)r * NCOL + col0];
            }
        }
        #pragma unroll
        for (int q = 0; q < 2; ++q) {
            #pragma unroll
            for (int k = 0; k < 8; ++k) {
                const int lr = b_w * 16 + lo * 8 + k;
                const int w_ = (lr & ~31) | ((lr & 31) ^ ((lr >> 5) & 15));
                stg[w_]        = v[q][k].x;      // column col0
                stg[w_ + 2048] = v[q][k].y;      // column col0+1
            }
            __syncthreads();
            #pragma unroll
            for (int s = 0; s < 16; ++s) {
                const int lr = P * 16 + s;
                const int w_ = (lr & ~31) | ((lr & 31) ^ ((lr >> 5) & 15));
                x[q * 16 + s] = stg[w2 * 2048 + w_];
            }
            __syncthreads();
        }
    }

    // ---- phase 1: normalized bitonic sort of my 32 contiguous elements ----
    #pragma unroll
    for (int k = 2; k <= EPT; k <<= 1) {
        #pragma unroll
        for (int base = 0; base < EPT; base += k) {
            #pragma unroll
            for (int o = 0; o < k / 2; ++o)
                cemin(x[base + o], x[base + k - 1 - o]);
        }
        #pragma unroll
        for (int j = k / 4; j >= 1; j >>= 1) {
            #pragma unroll
            for (int e = 0; e < EPT; ++e)
                if ((e & j) == 0) cemin(x[e], x[e | j]);
        }
    }

    // ---- phase 2: merges k = 64..2048, all in-wave, no barriers ----
    cross_merge<2>(x, L);
    cross_merge<4>(x, L);
    cross_merge<8>(x, L);
    cross_merge<16>(x, L);
    cross_merge<32>(x, L);
    cross_merge<64>(x, L);

    // ---- phase 3: k = 4096 merge across the wave pair, SYMMETRIC ----
    // Reversal pairs (P,e) <-> (127-P, 31-e). Two mirror-closed chunks:
    // c0: e in [0,8)+[24,32), c1: e in [8,24). Both waves write their 16,
    // both read the mirror (j' = 15-j), wp0 keeps min, wp1 keeps max.
    // Slot = P*16 + (j^(P&15)) -> 2-way banks (free). No idle segments.
    {
        float* xb = ls + (half * 2 + w2) * 2048;
        const int Pp = 127 - P;
        __syncthreads();                   // staging region is dead; safe to reuse
        #pragma unroll
        for (int c = 0; c < 2; ++c) {
            #pragma unroll
            for (int j = 0; j < 16; ++j) {
                const int e = (c == 0) ? ((j < 8) ? j : j + 16) : j + 8;
                xb[P * 16 + (j ^ (P & 15))] = x[e];
            }
            __syncthreads();
            if (wp == 0) {
                #pragma unroll
                for (int j = 0; j < 16; ++j) {
                    const int e = (c == 0) ? ((j < 8) ? j : j + 16) : j + 8;
                    const float y = xb[Pp * 16 + ((15 - j) ^ (Pp & 15))];
                    x[e] = fminf(x[e], y);     // lower global half keeps min
                }
            } else {
                #pragma unroll
                for (int j = 0; j < 16; ++j) {
                    const int e = (c == 0) ? ((j < 8) ? j : j + 16) : j + 8;
                    const float y = xb[Pp * 16 + ((15 - j) ^ (Pp & 15))];
                    x[e] = fmaxf(x[e], y);     // upper global half keeps max
                }
            }
            __syncthreads();
        }
        plains_down<32>(x, L);             // element distances 1024..32
        tail16(x);                         // 16..1
    }

    // ---- epilogue: SYMMETRIC split. pred parks e<16 (region A) and diffs
    // e>=16 against region B; obs parks e>=16 (region B) and diffs e<16
    // against region A. Both waves reduce + atomic. Swizzled slots, free. ----
    __syncthreads();                       // exchange region is dead
    {
        const int base = w2 * 2048 + P * 16;
        float s = 0.0f;
        if (half == 0) {
            #pragma unroll
            for (int e = 0; e < 16; ++e)
                ls[base + (e ^ (P & 15))] = x[e];                    // region A
        } else {
            #pragma unroll
            for (int e = 16; e < 32; ++e)
                ls[4096 + base + ((e - 16) ^ (P & 15))] = x[e];      // region B
        }
        __syncthreads();
        if (half == 0) {
            #pragma unroll
            for (int e = 16; e < 32; ++e)
                s += fabsf(x[e] - ls[4096 + base + ((e - 16) ^ (P & 15))]);
        } else {
            #pragma unroll
            for (int e = 0; e < 16; ++e)
                s += fabsf(x[e] - ls[base + (e ^ (P & 15))]);
        }
        #pragma unroll
        for (int off = 32; off > 0; off >>= 1)
            s += __shfl_down(s, off, 64);
        if (L == 0)
            atomicAdd(out, s * (1.0f / ((float)NT * (float)NCOL)));
    }
}

extern "C" void kernel_launch(void* const* d_in, const int* in_sizes, int n_in,
                              void* d_out, int out_size, void* d_ws, size_t ws_size,
                              hipStream_t stream) {
    const float* pred = (const float*)d_in[0];
    const float* obs  = (const float*)d_in[1];
    float* out = (float*)d_out;
    hipMemsetAsync(out, 0, sizeof(float), stream);
    wass_kernel<<<NBLOCKS, BLOCK, 0, stream>>>(pred, obs, out);
}

// Round 4
// 268.024 us; speedup vs baseline: 1.4758x; 1.4758x over previous
//
#include <hip/hip_runtime.h>

#define NT 4096          // time samples per column
#define NCOL 4096        // 512 traces * 8 channels
#define EPT 64           // elements per lane: one wave sorts one whole column
#define BLOCK 512        // 8 waves: waves 0-3 pred cols w, waves 4-7 obs cols w
#define NBLOCKS 1024     // 4096 cols / 4 cols per block

__device__ __forceinline__ float b2f(int i) { return __builtin_bit_cast(float, i); }
__device__ __forceinline__ int   f2b(float f) { return __builtin_bit_cast(int, f); }

// Cross-lane fetch of partner lane^XM's value.
// XM 1,2,3 (quad_perm), 7 (row_half_mirror), 8 (row_ror:8), 15 (row_mirror): DPP,
// VALU pipe, zero DS traffic. XM 4,16,31: ds_swizzle. XM 63: ds_bpermute.
template <int XM>
__device__ __forceinline__ float lx(float v) {
    const int i = f2b(v);
    int r;
    if constexpr (XM == 1)       r = __builtin_amdgcn_update_dpp(0, i, 0xB1,  0xF, 0xF, true);
    else if constexpr (XM == 2)  r = __builtin_amdgcn_update_dpp(0, i, 0x4E,  0xF, 0xF, true);
    else if constexpr (XM == 3)  r = __builtin_amdgcn_update_dpp(0, i, 0x1B,  0xF, 0xF, true);
    else if constexpr (XM == 7)  r = __builtin_amdgcn_update_dpp(0, i, 0x141, 0xF, 0xF, true);
    else if constexpr (XM == 8)  r = __builtin_amdgcn_update_dpp(0, i, 0x128, 0xF, 0xF, true);
    else if constexpr (XM == 15) r = __builtin_amdgcn_update_dpp(0, i, 0x140, 0xF, 0xF, true);
    else if constexpr (XM == 4)  r = __builtin_amdgcn_ds_swizzle(i, 0x101F);
    else if constexpr (XM == 16) r = __builtin_amdgcn_ds_swizzle(i, 0x401F);
    else if constexpr (XM == 31) r = __builtin_amdgcn_ds_swizzle(i, 0x7C1F);
    else {
        const int lane = (int)(threadIdx.x & 63);
        r = __builtin_amdgcn_ds_bpermute((lane ^ XM) << 2, i);
    }
    return b2f(r);
}

__device__ __forceinline__ void cemin(float& a, float& b) {
    const float lo = fminf(a, b);
    const float hi = fmaxf(a, b);
    a = lo; b = hi;
}
__device__ __forceinline__ float csel(float x, float y, bool keep_min) {
    return ((x < y) == keep_min) ? x : y;
}

// plain cross-lane stage, lane-xor M, same element index
template <int M>
__device__ __forceinline__ void plain_stage(float (&x)[EPT], int L) {
    const bool km = (L & M) == 0;
    #pragma unroll
    for (int e = 0; e < EPT; ++e) {
        const float y = lx<M>(x[e]);
        x[e] = csel(x[e], y, km);
    }
}

template <int M>
__device__ __forceinline__ void plains_down(float (&x)[EPT], int L) {
    plain_stage<M>(x, L);
    if constexpr (M > 1) plains_down<M / 2>(x, L);
}

// intra-thread plain stages j = 32..1, all ascending (normalized network)
__device__ __forceinline__ void tail32(float (&x)[EPT]) {
    #pragma unroll
    for (int j = 32; j >= 1; j >>= 1) {
        #pragma unroll
        for (int e = 0; e < EPT; ++e)
            if ((e & j) == 0) cemin(x[e], x[e | j]);
    }
}

// Normalized bitonic merge of size k = 64*K (K = 2..64), fully in-wave:
// reversal: partner lane L^(K-1), element mirror e<->63-e, keep-min if (L&K/2)==0;
// then plain lane-xor stages m=K/4..1; then intra-thread tail j=32..1.
template <int K>
__device__ __forceinline__ void cross_merge(float (&x)[EPT], int L) {
    const bool km = (L & (K >> 1)) == 0;
    #pragma unroll
    for (int e = 0; e < EPT / 2; ++e) {
        const float ylo = lx<K - 1>(x[EPT - 1 - e]);   // partner's mirrored element
        const float yhi = lx<K - 1>(x[e]);
        x[e]           = csel(x[e], ylo, km);
        x[EPT - 1 - e] = csel(x[EPT - 1 - e], yhi, km);
    }
    if constexpr (K >= 4) plains_down<K / 4>(x, L);
    tail32(x);
}

// LDS (one union, phases sequential):
//   staging: 2 halves x 4 cols x 1024-word chunk regions = 8192 words (32 KB)
//   epilogue strips: 4 cols x 64 lanes x 33 words        = 8448 words (33 KB)
// Total 33792 B -> 4 blocks/CU resident (vs 2 at 67.6 KB): 8 waves/SIMD.
#define LS_WORDS 8448

__global__ __launch_bounds__(512, 4) void wass_kernel(const float* __restrict__ pred,
                                                      const float* __restrict__ obs,
                                                      float* __restrict__ out) {
    __shared__ __align__(16) float ls[LS_WORDS];

    const int bid  = blockIdx.x;
    const int cb   = (bid & 7) * 128 + (bid >> 3);   // XCD-band col-block swizzle
    const int col0 = cb * 4;

    const int t    = threadIdx.x;
    const int half = t >> 8;           // 0 = pred, 1 = obs
    const int ht   = t & 255;          // thread within half
    const int w    = (t >> 6) & 3;     // column (0..3) this wave sorts
    const int L    = t & 63;           // lane

    const float* __restrict__ src = half ? obs : pred;

    // ---- staged load + transpose: 4 chunks of 1024 rows ----
    // Per (half, col): 1024-word region, word(lr) = (lr&~31)|((lr&31)^((lr>>5)&15)).
    // chunk q holds rows r = b*64 + q*16 + s  (lr = b*16 + s).
    // Writer thread ht owns lr = 4*ht+j  -> bank (4(ht&7)+j)^((ht>>3)&15): 2-way, free.
    // Reader lane L reads lr = L*16+s    -> bank 16(L&1)+(s^((L>>1)&15)): 2-way, free.
    float x[EPT];
    {
        float* stg = ls + half * 4096;
        #pragma unroll
        for (int q = 0; q < 4; ++q) {
            #pragma unroll
            for (int j = 0; j < 4; ++j) {
                const int lr = (ht << 2) | j;                      // 0..1023
                const int r  = (lr >> 4) * 64 + q * 16 + (lr & 15);
                const float4 v = *(const float4*)&src[(size_t)r * NCOL + col0];
                const int wd = (lr & ~31) | ((lr & 31) ^ ((lr >> 5) & 15));
                stg[wd]        = v.x;      // column col0
                stg[1024 + wd] = v.y;      // column col0+1
                stg[2048 + wd] = v.z;      // column col0+2
                stg[3072 + wd] = v.w;      // column col0+3
            }
            __syncthreads();
            #pragma unroll
            for (int s = 0; s < 16; ++s) {
                const int lr = L * 16 + s;
                const int wd = (lr & ~31) | ((lr & 31) ^ ((lr >> 5) & 15));
                x[q * 16 + s] = stg[w * 1024 + wd];
            }
            __syncthreads();
        }
    }

    // ---- phase 1: normalized bitonic sort of my 64 contiguous elements ----
    #pragma unroll
    for (int k = 2; k <= 64; k <<= 1) {
        #pragma unroll
        for (int base = 0; base < EPT; base += k) {
            #pragma unroll
            for (int o = 0; o < k / 2; ++o)
                cemin(x[base + o], x[base + k - 1 - o]);
        }
        #pragma unroll
        for (int j = k / 4; j >= 1; j >>= 1) {
            #pragma unroll
            for (int e = 0; e < EPT; ++e)
                if ((e & j) == 0) cemin(x[e], x[e | j]);
        }
    }

    // ---- phase 2: merges k = 128..4096, all in-wave, no barriers ----
    cross_merge<2>(x, L);
    cross_merge<4>(x, L);
    cross_merge<8>(x, L);
    cross_merge<16>(x, L);
    cross_merge<32>(x, L);
    cross_merge<64>(x, L);

    // ---- epilogue: two 32-element passes, scalar stride-33 strips.
    // bank = (L+e)&31 for both write and read: 2-way, free. ----
    __syncthreads();                   // staging region is dead; safe to reuse
    const int sb = (w * 64 + L) * 33;
    float s = 0.0f;
    #pragma unroll
    for (int hh = 0; hh < 2; ++hh) {
        if (half == 0) {
            #pragma unroll
            for (int e = 0; e < 32; ++e)
                ls[sb + e] = x[hh * 32 + e];
        }
        __syncthreads();
        if (half == 1) {
            #pragma unroll
            for (int e = 0; e < 32; ++e)
                s += fabsf(x[hh * 32 + e] - ls[sb + e]);
        }
        __syncthreads();
    }
    if (half == 1) {
        #pragma unroll
        for (int off = 32; off > 0; off >>= 1)
            s += __shfl_down(s, off, 64);
        if (L == 0)
            atomicAdd(out, s * (1.0f / ((float)NT * (float)NCOL)));
    }
}

extern "C" void kernel_launch(void* const* d_in, const int* in_sizes, int n_in,
                              void* d_out, int out_size, void* d_ws, size_t ws_size,
                              hipStream_t stream) {
    const float* pred = (const float*)d_in[0];
    const float* obs  = (const float*)d_in[1];
    float* out = (float*)d_out;
    hipMemsetAsync(out, 0, sizeof(float), stream);
    wass_kernel<<<NBLOCKS, BLOCK, 0, stream>>>(pred, obs, out);
}